// Round 1
// 1443.876 us; speedup vs baseline: 1.0759x; 1.0759x over previous
//
#include <hip/hip_runtime.h>

#define Bn 8
#define Sn 4096
#define Dn 1024
#define Mn 32
#define Kk 3
#define Rn 64
#define BSn (Bn*Sn)
#define NBK (Bn*Kk)   // 24

typedef unsigned short u16;
typedef short short8 __attribute__((ext_vector_type(8)));
typedef float f32x4 __attribute__((ext_vector_type(4)));

__device__ __forceinline__ u16 f2bf(float f){
  unsigned u = __builtin_bit_cast(unsigned, f);
  u += 0x7fffu + ((u >> 16) & 1u);          // RNE
  return (u16)(u >> 16);
}
__device__ __forceinline__ float bf2f(u16 h){
  unsigned u = ((unsigned)h) << 16;
  return __builtin_bit_cast(float, u);
}

__device__ __forceinline__ void cp16(const void* g, void* l){
  __builtin_amdgcn_global_load_lds(
      (const __attribute__((address_space(1))) void*)g,
      (__attribute__((address_space(3))) void*)l, 16, 0, 0);
}

__device__ __forceinline__ float2 block_sum2(float a, float b, float* red){
  #pragma unroll
  for (int off = 32; off > 0; off >>= 1){
    a += __shfl_down(a, off, 64);
    b += __shfl_down(b, off, 64);
  }
  int lane = threadIdx.x & 63, w = threadIdx.x >> 6;
  if (lane == 0){ red[w] = a; red[4+w] = b; }
  __syncthreads();
  float2 r;
  r.x = red[0]+red[1]+red[2]+red[3];
  r.y = red[4]+red[5]+red[6]+red[7];
  __syncthreads();
  return r;
}

__device__ __forceinline__ float3 block_sum3(float a, float b, float c, float* red){
  #pragma unroll
  for (int off = 32; off > 0; off >>= 1){
    a += __shfl_down(a, off, 64);
    b += __shfl_down(b, off, 64);
    c += __shfl_down(c, off, 64);
  }
  int lane = threadIdx.x & 63, w = threadIdx.x >> 6;
  if (lane == 0){ red[w] = a; red[4+w] = b; red[8+w] = c; }
  __syncthreads();
  float3 r;
  r.x = red[0]+red[1]+red[2]+red[3];
  r.y = red[4]+red[5]+red[6]+red[7];
  r.z = red[8]+red[9]+red[10]+red[11];
  __syncthreads();
  return r;
}

// ---------------- scores = pt_hidden @ anchor_w + anchor_b ----------------
__global__ __launch_bounds__(256) void k_scores(const float* __restrict__ pt,
    const float* __restrict__ aw, const float* __restrict__ ab, float* __restrict__ scores){
  int lane = threadIdx.x & 63, w = threadIdx.x >> 6;
  int row = blockIdx.x * 4 + w;
  const float4* x  = (const float4*)(pt + (size_t)row * Dn);
  const float4* wv = (const float4*)aw;
  float acc = 0.f;
  #pragma unroll
  for (int c = 0; c < 4; c++){
    int i = c * 64 + lane;
    float4 a = x[i], b = wv[i];
    acc += a.x*b.x + a.y*b.y + a.z*b.z + a.w*b.w;
  }
  #pragma unroll
  for (int off = 32; off > 0; off >>= 1) acc += __shfl_down(acc, off, 64);
  if (lane == 0) scores[row] = acc + ab[0];
}

// ---------------- top-3 per batch ----------------
__global__ __launch_bounds__(256) void k_top3(const float* __restrict__ scores, int* __restrict__ aidx){
  __shared__ float tv[256*3];
  __shared__ int   ti[256*3];
  int b = blockIdx.x, t = threadIdx.x;
  float v[3] = {-1e38f, -1e38f, -1e38f};
  int  id[3] = {0x7fffffff, 0x7fffffff, 0x7fffffff};
  for (int s = t; s < Sn; s += 256){
    float sc = scores[b*Sn + s];
    if (sc > v[0] || (sc == v[0] && s < id[0])){ v[2]=v[1]; id[2]=id[1]; v[1]=v[0]; id[1]=id[0]; v[0]=sc; id[0]=s; }
    else if (sc > v[1] || (sc == v[1] && s < id[1])){ v[2]=v[1]; id[2]=id[1]; v[1]=sc; id[1]=s; }
    else if (sc > v[2] || (sc == v[2] && s < id[2])){ v[2]=sc; id[2]=s; }
  }
  for (int j = 0; j < 3; j++){ tv[t*3+j] = v[j]; ti[t*3+j] = id[j]; }
  __syncthreads();
  if (t == 0){
    float bv[3] = {-1e38f, -1e38f, -1e38f};
    int   bi[3] = {0x7fffffff, 0x7fffffff, 0x7fffffff};
    for (int c = 0; c < 256*3; c++){
      float sc = tv[c]; int ii = ti[c];
      if (sc > bv[0] || (sc == bv[0] && ii < bi[0])){ bv[2]=bv[1]; bi[2]=bi[1]; bv[1]=bv[0]; bi[1]=bi[0]; bv[0]=sc; bi[0]=ii; }
      else if (sc > bv[1] || (sc == bv[1] && ii < bi[1])){ bv[2]=bv[1]; bi[2]=bi[1]; bv[1]=sc; bi[1]=ii; }
      else if (sc > bv[2] || (sc == bv[2] && ii < bi[2])){ bv[2]=sc; bi[2]=ii; }
    }
    for (int j = 0; j < 3; j++) aidx[b*3+j] = bi[j];
  }
}

// ---------------- adapter phase A: per (b,k): gather anchor, softmax weights, invZ ----------------
__global__ __launch_bounds__(256) void k_adapter_w(const float* __restrict__ pt,
    const float* __restrict__ cent, const float* __restrict__ pp, const int* __restrict__ aidx,
    float* __restrict__ A24, float* __restrict__ gw, float* __restrict__ invZ){
  __shared__ float a_lds[Dn];
  __shared__ float logitv[Mn];
  __shared__ float red[12];
  int bk = blockIdx.x; int b = bk / Kk;
  int t = threadIdx.x;
  int p = aidx[bk];
  const float* arow = pt + ((size_t)b*Sn + p) * Dn;
  for (int d = t; d < Dn; d += 256){ float v = arow[d]; a_lds[d] = v; A24[(size_t)bk*Dn + d] = v; }
  __syncthreads();
  float ss = 0.f;
  for (int d = t; d < Dn; d += 256){ float v = a_lds[d]; ss += v*v; }
  float2 rr0 = block_sum2(ss, 0.f, red);
  float na = fmaxf(sqrtf(rr0.x), 1e-6f);
  int lane = t & 63, w = t >> 6;
  for (int mi = 0; mi < 8; mi++){
    int m = w*8 + mi;
    const float* c = cent + (size_t)m * Dn;
    float dt = 0.f, cs = 0.f;
    for (int d = lane; d < Dn; d += 64){ float cv = c[d]; dt += a_lds[d]*cv; cs += cv*cv; }
    #pragma unroll
    for (int off = 32; off > 0; off >>= 1){ dt += __shfl_down(dt, off, 64); cs += __shfl_down(cs, off, 64); }
    if (lane == 0){ float nc = fmaxf(sqrtf(cs), 1e-6f); logitv[m] = dt / (na * nc); }
  }
  __syncthreads();
  if (t == 0){
    float mx = -1e30f;
    for (int m = 0; m < Mn; m++) mx = fmaxf(mx, logitv[m]);
    float sm = 0.f, e[Mn];
    for (int m = 0; m < Mn; m++){ e[m] = expf(logitv[m]-mx); sm += e[m]; }
    float inv = 1.f / sm;
    for (int m = 0; m < Mn; m++) gw[bk*Mn + m] = e[m] * inv;
  }
  // spread normalizer Z
  {
    float zp = 0.f; float ppp = pp[p];
    for (int s2 = t; s2 < Sn; s2 += 256){
      float dd = fabsf(pp[s2] - ppp);
      if (dd <= 8.0f) zp += expf(-dd * 0.125f);
    }
    float2 zr = block_sum2(zp, 0.f, red);
    if (t == 0) invZ[bk] = 1.f / zr.x;
  }
}

// ---------------- low partials: block (dc, m): part[bk][m][dc][r] = sum_{d in chunk} a[bk][d]*ta[m][d][r]
__global__ __launch_bounds__(256) void k_lowpart(const float* __restrict__ ta,
    const float* __restrict__ A24, float* __restrict__ part_low){
  __shared__ float ta_s[64*64];       // [d][r]
  __shared__ float a_s[NBK*64];       // [bk][d]
  int dc = blockIdx.x, m = blockIdx.y;
  int t = threadIdx.x;
  int d0 = dc * 64;
  const float4* src = (const float4*)(ta + ((size_t)m*Dn + d0) * Rn);
  float4* dst = (float4*)ta_s;
  #pragma unroll
  for (int c = 0; c < 4; c++) dst[t + c*256] = src[t + c*256];
  for (int idx = t; idx < NBK*64; idx += 256){
    int bk = idx >> 6, dl = idx & 63;
    a_s[idx] = A24[(size_t)bk*Dn + d0 + dl];
  }
  __syncthreads();
  int r = t & 63, g = t >> 6;
  #pragma unroll
  for (int j = 0; j < 6; j++){
    int bk = g*6 + j;
    float acc = 0.f;
    #pragma unroll 8
    for (int d = 0; d < 64; d++) acc += a_s[bk*64 + d] * ta_s[d*64 + r];
    part_low[(((size_t)bk*Mn + m)*16 + dc)*64 + r] = acc;
  }
}

// ---------------- low final: low[bk][r] = sum_m w * sum_dc part ----------------
__global__ __launch_bounds__(64) void k_lowfin(const float* __restrict__ part_low,
    const float* __restrict__ gw, float* __restrict__ lowb){
  int bk = blockIdx.x, r = threadIdx.x;
  float acc = 0.f;
  for (int m = 0; m < Mn; m++){
    float s = 0.f;
    #pragma unroll
    for (int dc = 0; dc < 16; dc++)
      s += part_low[(((size_t)bk*Mn + m)*16 + dc)*64 + r];
    acc += gw[bk*Mn + m] * s;
  }
  lowb[bk*64 + r] = acc;
}

// ---------------- translated partials: block (dc, m): transp[bk][m][d] = sum_r tb[m][d][r]*low[bk][r]
__global__ __launch_bounds__(256) void k_transpart(const float* __restrict__ tb,
    const float* __restrict__ lowb, float* __restrict__ transp){
  __shared__ float tb_t[64*65];       // [r][d], padded
  __shared__ float low_s[NBK*64];
  int dc = blockIdx.x, m = blockIdx.y;
  int t = threadIdx.x;
  int d0 = dc * 64;
  const float* src = tb + ((size_t)m*Dn + d0) * Rn;
  for (int idx = t; idx < 4096; idx += 256){
    int d = idx >> 6, r = idx & 63;
    tb_t[r*65 + d] = src[idx];
  }
  for (int idx = t; idx < NBK*64; idx += 256) low_s[idx] = lowb[idx];
  __syncthreads();
  int dl = t & 63, g = t >> 6;
  #pragma unroll
  for (int j = 0; j < 6; j++){
    int bk = g*6 + j;
    float acc = 0.f;
    #pragma unroll 8
    for (int r = 0; r < 64; r++) acc += tb_t[r*65 + dl] * low_s[bk*64 + r];
    transp[((size_t)bk*Mn + m)*Dn + d0 + dl] = acc;
  }
}

// ---------------- translated final: transl[bk][d] = sum_m w*transp ----------------
__global__ __launch_bounds__(256) void k_transfin(const float* __restrict__ transp,
    const float* __restrict__ gw, float* __restrict__ transl){
  int bk = blockIdx.x, t = threadIdx.x;
  for (int d = t; d < Dn; d += 256){
    float acc = 0.f;
    #pragma unroll 8
    for (int m = 0; m < Mn; m++)
      acc += gw[bk*Mn + m] * transp[((size_t)bk*Mn + m)*Dn + d];
    transl[(size_t)bk*Dn + d] = acc;
  }
}

// ---------------- transpose f32 [Ks][1024] -> bf16 [1024][Ks] ----------------
__global__ __launch_bounds__(256) void k_transpose(const float* __restrict__ src,
    u16* __restrict__ dst, int Ks){
  __shared__ float tile[32][33];
  int kb = blockIdx.x * 32, nb = blockIdx.y * 32;
  int tx = threadIdx.x & 31, ty = threadIdx.x >> 5;
  #pragma unroll
  for (int r = 0; r < 32; r += 8)
    tile[ty+r][tx] = src[(size_t)(kb+ty+r) * Dn + nb + tx];
  __syncthreads();
  #pragma unroll
  for (int r = 0; r < 32; r += 8)
    dst[(size_t)(nb+ty+r) * Ks + kb + tx] = f2bf(tile[tx][ty+r]);
}

// ---------------- per-row: spread update + 3 LN + gate ----------------
__global__ __launch_bounds__(256) void k_rows(
    const float* __restrict__ ts, const float* __restrict__ pt,
    const float* __restrict__ stab, const float* __restrict__ transl,
    const int* __restrict__ aidx, const float* __restrict__ invZ,
    const float* __restrict__ pp,
    const float* __restrict__ og, const float* __restrict__ ob,
    const float* __restrict__ tgp, const float* __restrict__ tbp,
    const float* __restrict__ pgp, const float* __restrict__ pbp,
    float* __restrict__ ts_aug_out, u16* __restrict__ Xcat, float* __restrict__ gate){
  __shared__ float red[12];
  int row = blockIdx.x; int b = row >> 12; int s = row & 4095;
  int t = threadIdx.x;
  size_t base = (size_t)row * Dn;
  const float4 xin = *(const float4*)(ts + base + 4*t);
  float x0 = xin.x, x1 = xin.y, x2 = xin.z, x3 = xin.w;
  float pps = pp[s];
  for (int k = 0; k < Kk; k++){
    int p = aidx[b*Kk + k];
    float dd = fabsf(pps - pp[p]);
    if (dd <= 8.0f){
      float coef = expf(-dd * 0.125f) * invZ[b*Kk + k];
      const float4 tr = *(const float4*)(transl + ((size_t)(b*Kk + k)) * Dn + 4*t);
      x0 += coef*tr.x; x1 += coef*tr.y; x2 += coef*tr.z; x3 += coef*tr.w;
    }
  }
  float2 r = block_sum2(x0+x1+x2+x3, x0*x0+x1*x1+x2*x2+x3*x3, red);
  float mu = r.x * (1.f/Dn); float var = r.y * (1.f/Dn) - mu*mu;
  float rs = 1.f / sqrtf(var + 1e-5f);
  float4 g4 = *(const float4*)(og + 4*t), b4 = *(const float4*)(ob + 4*t);
  float a0 = (x0-mu)*rs*g4.x + b4.x;
  float a1 = (x1-mu)*rs*g4.y + b4.y;
  float a2 = (x2-mu)*rs*g4.z + b4.z;
  float a3 = (x3-mu)*rs*g4.w + b4.w;
  float4 sto; sto.x=a0; sto.y=a1; sto.z=a2; sto.w=a3;
  *(float4*)(ts_aug_out + base + 4*t) = sto;
  r = block_sum2(a0+a1+a2+a3, a0*a0+a1*a1+a2*a2+a3*a3, red);
  mu = r.x * (1.f/Dn); var = r.y * (1.f/Dn) - mu*mu;
  rs = 1.f / sqrtf(var + 1e-5f);
  g4 = *(const float4*)(tgp + 4*t); b4 = *(const float4*)(tbp + 4*t);
  float t0 = (a0-mu)*rs*g4.x + b4.x;
  float t1 = (a1-mu)*rs*g4.y + b4.y;
  float t2 = (a2-mu)*rs*g4.z + b4.z;
  float t3 = (a3-mu)*rs*g4.w + b4.w;
  const float4 pv = *(const float4*)(pt + base + 4*t);
  r = block_sum2(pv.x+pv.y+pv.z+pv.w, pv.x*pv.x+pv.y*pv.y+pv.z*pv.z+pv.w*pv.w, red);
  mu = r.x * (1.f/Dn); var = r.y * (1.f/Dn) - mu*mu;
  rs = 1.f / sqrtf(var + 1e-5f);
  g4 = *(const float4*)(pgp + 4*t); b4 = *(const float4*)(pbp + 4*t);
  float p0 = (pv.x-mu)*rs*g4.x + b4.x;
  float p1 = (pv.y-mu)*rs*g4.y + b4.y;
  float p2 = (pv.z-mu)*rs*g4.z + b4.z;
  float p3 = (pv.w-mu)*rs*g4.w + b4.w;
  ushort4 pk;
  pk.x = f2bf(t0); pk.y = f2bf(t1); pk.z = f2bf(t2); pk.w = f2bf(t3);
  *(ushort4*)(Xcat + (size_t)row*2048 + 4*t) = pk;
  pk.x = f2bf(p0); pk.y = f2bf(p1); pk.z = f2bf(p2); pk.w = f2bf(p3);
  *(ushort4*)(Xcat + (size_t)row*2048 + Dn + 4*t) = pk;
  float3 rr = block_sum3(t0*p0+t1*p1+t2*p2+t3*p3,
                         t0*t0+t1*t1+t2*t2+t3*t3,
                         p0*p0+p1*p1+p2*p2+p3*p3, red);
  if (t == 0){
    float cosv = rr.x / (fmaxf(sqrtf(rr.y), 1e-6f) * fmaxf(sqrtf(rr.z), 1e-6f));
    float ag = 0.5f * (1.f + cosv);
    float z = (ag - 0.72f) * 5.f;
    float focus = 0.2f + 0.8f * expf(-0.5f*z*z);
    gate[row] = ag * focus * stab[row];
  }
}

// ---------------- 256x256 bf16 MFMA GEMM, 8-phase schedule (T1+T2+T3+T4+T5) ----------------
// A: [M][K] bf16 row-major, Bt: [N=1024][K] bf16 row-major. Grid = 512 = (M/256=128) x (N/256=4).
// 8 waves (2M x 4N), per-wave output 128x64 split as 2 half-pieces of 64 rows (one per A-half).
// LDS 128KB: A dbuf 2x(2 halves x 128rows x 128B), B same at +64KB. 16B-chunk XOR swizzle
// chunk^= (row&7), applied on pre-swizzled global source (linear global_load_lds dest) and
// on ds_read addresses. Per K-tile (BK=64): 4 phases, each {ds_read subtile | stage 1 half-tile
// | barrier | lgkmcnt(0) | setprio(1) 16xMFMA setprio(0) | barrier}; one counted
// s_waitcnt vmcnt(4) per K-tile boundary (staging leads consumption by 5-6 phases; verified
// slot discipline: every slot's last read is >=1 barrier before its restage issue).
// mode 0: out0 = acc + sbias[n] + gate[m]*Wlast[n]
// mode 1: dts[m,n] += blend*gate[m]*acc
// mode 2: dpt[m,n] = ptin[m,n] + blend*gate[m]*acc
__global__ __launch_bounds__(512, 2) void k_gemm(
    const u16* __restrict__ A, const u16* __restrict__ Bt, int K, int mode,
    float* __restrict__ out0, const float* __restrict__ sbias, const float* __restrict__ Wlast,
    const float* __restrict__ gate, float* __restrict__ dts,
    const float* __restrict__ ptin, float* __restrict__ dpt, const float* __restrict__ bscale){
  __shared__ __attribute__((aligned(16))) char smem[131072];
  const int NT = K >> 6;
  const int tid = threadIdx.x;
  const int lane = tid & 63, w = tid >> 6;
  const int wm = w >> 2, wn = w & 3;
  const int r15 = lane & 15, quad = lane >> 4;
  // bijective XCD swizzle (512 % 8 == 0): consecutive blocks on one XCD share the B panel
  const int bid = blockIdx.x;
  const int bm = (bid & 7) * 16 + ((bid >> 3) & 15);
  const int bn = bid >> 7;
  const int m0 = bm * 256, n0 = bn * 256;

  // --- staging: pre-swizzled global source, linear LDS dest (rule #21) ---
  const int row0 = tid >> 3, j0 = tid & 7;
  const int js = j0 ^ (row0 & 7);
  const size_t rowbytes = (size_t)K * 2;
  const char* gA = (const char*)A + (size_t)(m0 + row0) * rowbytes + js * 16;
  const char* gB = (const char*)Bt + (size_t)(n0 + row0) * rowbytes + js * 16;
  const size_t rstep64 = rowbytes << 6;   // 64 rows
  char* lA = smem + tid * 16;
  char* lB = smem + 65536 + tid * 16;

  auto stgA = [&](int half, int tile, int buf){
    const char* s = gA + (size_t)half * (rstep64 << 1) + (size_t)tile * 128;
    char* d = lA + buf * 32768 + half * 16384;
    cp16(s, d); cp16(s + rstep64, d + 8192);
  };
  auto stgB = [&](int half, int tile, int buf){
    const char* s = gB + (size_t)half * (rstep64 << 1) + (size_t)tile * 128;
    char* d = lB + buf * 32768 + half * 16384;
    cp16(s, d); cp16(s + rstep64, d + 8192);
  };

  // --- ds_read fragment byte offsets (same XOR swizzle) ---
  int aoff[4][2], boff[2][2];
  #pragma unroll
  for (int fi = 0; fi < 4; fi++){
    int rl = wm*64 + fi*16 + r15;
    #pragma unroll
    for (int ks = 0; ks < 2; ks++)
      aoff[fi][ks] = rl*128 + ((((ks<<2) + quad) ^ (r15 & 7)) << 4);
  }
  #pragma unroll
  for (int fj = 0; fj < 2; fj++){
    int rn = wn*32 + fj*16 + r15;
    #pragma unroll
    for (int ks = 0; ks < 2; ks++)
      boff[fj][ks] = rn*128 + ((((ks<<2) + quad) ^ (r15 & 7)) << 4);
  }

  short8 ar[4][2];        // current A-piece fragments [fi][ks]
  short8 br[2][2][2];     // both B pieces kept live    [piece][fj][ks]
  f32x4 acc[8][4];
  #pragma unroll
  for (int i = 0; i < 8; i++)
    #pragma unroll
    for (int j = 0; j < 4; j++){ f32x4 z = {0.f,0.f,0.f,0.f}; acc[i][j] = z; }

  auto rdA = [&](int ph, int buf){
    #pragma unroll
    for (int fi = 0; fi < 4; fi++)
      #pragma unroll
      for (int ks = 0; ks < 2; ks++)
        ar[fi][ks] = *(const short8*)(smem + buf*32768 + ph*16384 + aoff[fi][ks]);
  };
  auto rdB = [&](int p, int buf){
    #pragma unroll
    for (int fj = 0; fj < 2; fj++)
      #pragma unroll
      for (int ks = 0; ks < 2; ks++)
        br[p][fj][ks] = *(const short8*)(smem + 65536 + buf*32768 + p*16384 + boff[fj][ks]);
  };
  auto mma16 = [&](int ap, int bp){
    __builtin_amdgcn_s_barrier();
    asm volatile("s_waitcnt lgkmcnt(0)" ::: "memory");
    __builtin_amdgcn_sched_barrier(0);
    __builtin_amdgcn_s_setprio(1);
    #pragma unroll
    for (int fi = 0; fi < 4; fi++)
      #pragma unroll
      for (int fj = 0; fj < 2; fj++)
        #pragma unroll
        for (int ks = 0; ks < 2; ks++)
          acc[ap*4+fi][bp*2+fj] = __builtin_amdgcn_mfma_f32_16x16x32_bf16(
              ar[fi][ks], br[bp][fj][ks], acc[ap*4+fi][bp*2+fj], 0, 0, 0);
    __builtin_amdgcn_s_setprio(0);
  };

  // --- prologue: tile0 fully (buf0) + tile1's A-h0, B-h1 (buf1) ---
  stgA(0, 0, 0); stgA(1, 0, 0); stgB(0, 0, 0); stgB(1, 0, 0);
  stgA(0, 1, 1); stgB(1, 1, 1);
  asm volatile("s_waitcnt vmcnt(4)" ::: "memory");
  __builtin_amdgcn_s_barrier();

  auto tileStep = [&](int t, int buf){
    // ph1: (A-half0 x B-half0)
    rdA(0, buf); rdB(0, buf);
    if (t+1 < NT) stgA(1, t+1, buf^1);
    mma16(0, 0);
    __builtin_amdgcn_s_barrier();
    // ph2: (A-half0 x B-half1)
    rdB(1, buf);
    if (t+1 < NT) stgB(0, t+1, buf^1);
    mma16(0, 1);
    __builtin_amdgcn_s_barrier();
    // ph3: (A-half1 x B-half1)
    rdA(1, buf);
    if (t+2 < NT) stgA(0, t+2, buf);
    mma16(1, 1);
    __builtin_amdgcn_s_barrier();
    // ph4: (A-half1 x B-half0), B-h0 regs kept from ph1
    if (t+2 < NT) stgB(1, t+2, buf);
    mma16(1, 0);
    if (t+2 < NT){ asm volatile("s_waitcnt vmcnt(4)" ::: "memory"); }
    else         { asm volatile("s_waitcnt vmcnt(0)" ::: "memory"); }
    __builtin_amdgcn_s_barrier();
  };
  for (int t = 0; t < NT; t += 2){ tileStep(t, 0); tileStep(t+1, 1); }

  // --- epilogue ---
  float blend = 0.f;
  if (mode != 0) blend = 0.35f / (1.f + expf(-bscale[0]));
  #pragma unroll
  for (int mi = 0; mi < 8; mi++){
    int rowb = m0 + (mi>>2)*128 + wm*64 + (mi&3)*16 + quad*4;
    #pragma unroll
    for (int nj = 0; nj < 4; nj++){
      int col = n0 + (nj>>1)*128 + wn*32 + (nj&1)*16 + r15;
      #pragma unroll
      for (int rg = 0; rg < 4; rg++){
        int rw = rowb + rg;
        size_t idx = (size_t)rw * Dn + col;
        float v = acc[mi][nj][rg];
        if (mode == 0){
          out0[idx] = v + sbias[col] + gate[rw] * Wlast[col];
        } else if (mode == 1){
          dts[idx] = dts[idx] + blend * gate[rw] * v;
        } else {
          dpt[idx] = ptin[idx] + blend * gate[rw] * v;
        }
      }
    }
  }
}

// ---------------- causal pool (k=3) + diffs vs tsn/ptn, bf16 ----------------
__global__ __launch_bounds__(256) void k_pooldiff(const float* __restrict__ sh,
    const u16* __restrict__ Xcat, u16* __restrict__ Xts, u16* __restrict__ Xpt){
  int row = blockIdx.x; int s = row & 4095; int t = threadIdx.x;
  size_t base = (size_t)row * Dn + 4*t;
  int rm1 = (s >= 1) ? row-1 : row;
  int rm2 = (s >= 2) ? row-2 : rm1;
  float4 a = *(const float4*)(sh + base);
  float4 b = *(const float4*)(sh + (size_t)rm1*Dn + 4*t);
  float4 c = *(const float4*)(sh + (size_t)rm2*Dn + 4*t);
  float p0 = (a.x+b.x+c.x)*(1.f/3.f);
  float p1 = (a.y+b.y+c.y)*(1.f/3.f);
  float p2 = (a.z+b.z+c.z)*(1.f/3.f);
  float p3 = (a.w+b.w+c.w)*(1.f/3.f);
  ushort4 tn = *(const ushort4*)(Xcat + (size_t)row*2048 + 4*t);
  ushort4 pn = *(const ushort4*)(Xcat + (size_t)row*2048 + Dn + 4*t);
  ushort4 o;
  o.x = f2bf(p0 - bf2f(tn.x)); o.y = f2bf(p1 - bf2f(tn.y));
  o.z = f2bf(p2 - bf2f(tn.z)); o.w = f2bf(p3 - bf2f(tn.w));
  *(ushort4*)(Xts + base) = o;
  o.x = f2bf(p0 - bf2f(pn.x)); o.y = f2bf(p1 - bf2f(pn.y));
  o.z = f2bf(p2 - bf2f(pn.z)); o.w = f2bf(p3 - bf2f(pn.w));
  *(ushort4*)(Xpt + base) = o;
}

extern "C" void kernel_launch(void* const* d_in, const int* in_sizes, int n_in,
                              void* d_out, int out_size, void* d_ws, size_t ws_size,
                              hipStream_t stream){
  const float* pt   = (const float*)d_in[0];
  const float* ts   = (const float*)d_in[1];
  const float* pp   = (const float*)d_in[2];
  const float* cent = (const float*)d_in[3];
  const float* stab = (const float*)d_in[4];
  const float* aw   = (const float*)d_in[5];
  const float* ab   = (const float*)d_in[6];
  const float* ta   = (const float*)d_in[7];
  const float* tb   = (const float*)d_in[8];
  const float* og   = (const float*)d_in[9];
  const float* ob   = (const float*)d_in[10];
  const float* tg   = (const float*)d_in[11];
  const float* tbn  = (const float*)d_in[12];
  const float* pg   = (const float*)d_in[13];
  const float* pb   = (const float*)d_in[14];
  const float* sW   = (const float*)d_in[15];
  const float* sb   = (const float*)d_in[16];
  const float* tsW  = (const float*)d_in[17];
  const float* ptW  = (const float*)d_in[18];
  const float* bsc  = (const float*)d_in[19];
  float* out_ts = (float*)d_out;
  float* out_pt = out_ts + (size_t)BSn * Dn;

  char* wbase = (char*)d_ws; size_t off = 0;
  auto alloc = [&](size_t bytes) -> void* {
    void* p = wbase + off;
    off += (bytes + 255) & ~(size_t)255;
    return p;
  };
  float* scores  = (float*)alloc((size_t)BSn * 4);
  int*   aidx    = (int*)  alloc(256);
  float* invZ    = (float*)alloc(256);
  float* transl  = (float*)alloc((size_t)NBK*Dn * 4);
  float* gate    = (float*)alloc((size_t)BSn * 4);
  float* A24     = (float*)alloc((size_t)NBK*Dn * 4);
  float* gw      = (float*)alloc((size_t)NBK*Mn * 4);
  float* part_low= (float*)alloc((size_t)NBK*Mn*16*64 * 4);
  float* lowb    = (float*)alloc((size_t)NBK*64 * 4);
  float* transp  = (float*)alloc((size_t)NBK*Mn*Dn * 4);
  u16*   Xcat    = (u16*)  alloc((size_t)BSn * 2048 * 2);
  float* shmem   = (float*)alloc((size_t)BSn * Dn * 4);
  u16*   Xts     = (u16*)  alloc((size_t)BSn * Dn * 2);
  u16*   Xpt     = (u16*)  alloc((size_t)BSn * Dn * 2);
  u16*   WtS     = (u16*)  alloc((size_t)Dn * 2048 * 2);
  u16*   WtT     = (u16*)  alloc((size_t)Dn * Dn * 2);
  u16*   WtP     = (u16*)  alloc((size_t)Dn * Dn * 2);

  k_scores<<<BSn/4, 256, 0, stream>>>(pt, aw, ab, scores);
  k_top3<<<Bn, 256, 0, stream>>>(scores, aidx);
  k_adapter_w<<<NBK, 256, 0, stream>>>(pt, cent, pp, aidx, A24, gw, invZ);
  k_lowpart<<<dim3(16, Mn), 256, 0, stream>>>(ta, A24, part_low);
  k_lowfin<<<NBK, 64, 0, stream>>>(part_low, gw, lowb);
  k_transpart<<<dim3(16, Mn), 256, 0, stream>>>(tb, lowb, transp);
  k_transfin<<<NBK, 256, 0, stream>>>(transp, gw, transl);
  k_transpose<<<dim3(64,32), 256, 0, stream>>>(sW, WtS, 2048);
  k_transpose<<<dim3(32,32), 256, 0, stream>>>(tsW, WtT, 1024);
  k_transpose<<<dim3(32,32), 256, 0, stream>>>(ptW, WtP, 1024);
  k_rows<<<BSn, 256, 0, stream>>>(ts, pt, stab, transl, aidx, invZ, pp,
                                  og, ob, tg, tbn, pg, pb, out_ts, Xcat, gate);
  k_gemm<<<512, 512, 0, stream>>>(Xcat, WtS, 2048, 0,
      shmem, sb, sW + (size_t)2048*Dn, gate, nullptr, nullptr, nullptr, bsc);
  k_pooldiff<<<BSn, 256, 0, stream>>>(shmem, Xcat, Xts, Xpt);
  k_gemm<<<512, 512, 0, stream>>>(Xts, WtT, 1024, 1,
      nullptr, nullptr, nullptr, gate, out_ts, nullptr, nullptr, bsc);
  k_gemm<<<512, 512, 0, stream>>>(Xpt, WtP, 1024, 2,
      nullptr, nullptr, nullptr, gate, nullptr, pt, out_pt, bsc);
}

// Round 2
// 1310.484 us; speedup vs baseline: 1.1854x; 1.1018x over previous
//
#include <hip/hip_runtime.h>

#define Bn 8
#define Sn 4096
#define Dn 1024
#define Mn 32
#define Kk 3
#define Rn 64
#define BSn (Bn*Sn)
#define NBK (Bn*Kk)   // 24

typedef unsigned short u16;
typedef short short8 __attribute__((ext_vector_type(8)));
typedef float f32x4 __attribute__((ext_vector_type(4)));

__device__ __forceinline__ u16 f2bf(float f){
  unsigned u = __builtin_bit_cast(unsigned, f);
  u += 0x7fffu + ((u >> 16) & 1u);          // RNE
  return (u16)(u >> 16);
}
__device__ __forceinline__ float bf2f(u16 h){
  unsigned u = ((unsigned)h) << 16;
  return __builtin_bit_cast(float, u);
}

__device__ __forceinline__ void cp16(const void* g, void* l){
  __builtin_amdgcn_global_load_lds(
      (const __attribute__((address_space(1))) void*)g,
      (__attribute__((address_space(3))) void*)l, 16, 0, 0);
}

__device__ __forceinline__ float2 block_sum2(float a, float b, float* red){
  #pragma unroll
  for (int off = 32; off > 0; off >>= 1){
    a += __shfl_down(a, off, 64);
    b += __shfl_down(b, off, 64);
  }
  int lane = threadIdx.x & 63, w = threadIdx.x >> 6;
  if (lane == 0){ red[w] = a; red[4+w] = b; }
  __syncthreads();
  float2 r;
  r.x = red[0]+red[1]+red[2]+red[3];
  r.y = red[4]+red[5]+red[6]+red[7];
  __syncthreads();
  return r;
}

__device__ __forceinline__ float3 block_sum3(float a, float b, float c, float* red){
  #pragma unroll
  for (int off = 32; off > 0; off >>= 1){
    a += __shfl_down(a, off, 64);
    b += __shfl_down(b, off, 64);
    c += __shfl_down(c, off, 64);
  }
  int lane = threadIdx.x & 63, w = threadIdx.x >> 6;
  if (lane == 0){ red[w] = a; red[4+w] = b; red[8+w] = c; }
  __syncthreads();
  float3 r;
  r.x = red[0]+red[1]+red[2]+red[3];
  r.y = red[4]+red[5]+red[6]+red[7];
  r.z = red[8]+red[9]+red[10]+red[11];
  __syncthreads();
  return r;
}

// ---------------- scores = pt_hidden @ anchor_w + anchor_b ----------------
__global__ __launch_bounds__(256) void k_scores(const float* __restrict__ pt,
    const float* __restrict__ aw, const float* __restrict__ ab, float* __restrict__ scores){
  int lane = threadIdx.x & 63, w = threadIdx.x >> 6;
  int row = blockIdx.x * 4 + w;
  const float4* x  = (const float4*)(pt + (size_t)row * Dn);
  const float4* wv = (const float4*)aw;
  float acc = 0.f;
  #pragma unroll
  for (int c = 0; c < 4; c++){
    int i = c * 64 + lane;
    float4 a = x[i], b = wv[i];
    acc += a.x*b.x + a.y*b.y + a.z*b.z + a.w*b.w;
  }
  #pragma unroll
  for (int off = 32; off > 0; off >>= 1) acc += __shfl_down(acc, off, 64);
  if (lane == 0) scores[row] = acc + ab[0];
}

// ---------------- top-3 per batch ----------------
__global__ __launch_bounds__(256) void k_top3(const float* __restrict__ scores, int* __restrict__ aidx){
  __shared__ float tv[256*3];
  __shared__ int   ti[256*3];
  int b = blockIdx.x, t = threadIdx.x;
  float v[3] = {-1e38f, -1e38f, -1e38f};
  int  id[3] = {0x7fffffff, 0x7fffffff, 0x7fffffff};
  for (int s = t; s < Sn; s += 256){
    float sc = scores[b*Sn + s];
    if (sc > v[0] || (sc == v[0] && s < id[0])){ v[2]=v[1]; id[2]=id[1]; v[1]=v[0]; id[1]=id[0]; v[0]=sc; id[0]=s; }
    else if (sc > v[1] || (sc == v[1] && s < id[1])){ v[2]=v[1]; id[2]=id[1]; v[1]=sc; id[1]=s; }
    else if (sc > v[2] || (sc == v[2] && s < id[2])){ v[2]=sc; id[2]=s; }
  }
  for (int j = 0; j < 3; j++){ tv[t*3+j] = v[j]; ti[t*3+j] = id[j]; }
  __syncthreads();
  if (t == 0){
    float bv[3] = {-1e38f, -1e38f, -1e38f};
    int   bi[3] = {0x7fffffff, 0x7fffffff, 0x7fffffff};
    for (int c = 0; c < 256*3; c++){
      float sc = tv[c]; int ii = ti[c];
      if (sc > bv[0] || (sc == bv[0] && ii < bi[0])){ bv[2]=bv[1]; bi[2]=bi[1]; bv[1]=bv[0]; bi[1]=bi[0]; bv[0]=sc; bi[0]=ii; }
      else if (sc > bv[1] || (sc == bv[1] && ii < bi[1])){ bv[2]=bv[1]; bi[2]=bi[1]; bv[1]=sc; bi[1]=ii; }
      else if (sc > bv[2] || (sc == bv[2] && ii < bi[2])){ bv[2]=sc; bi[2]=ii; }
    }
    for (int j = 0; j < 3; j++) aidx[b*3+j] = bi[j];
  }
}

// ---------------- adapter phase A: per (b,k): gather anchor, softmax weights, invZ ----------------
__global__ __launch_bounds__(256) void k_adapter_w(const float* __restrict__ pt,
    const float* __restrict__ cent, const float* __restrict__ pp, const int* __restrict__ aidx,
    float* __restrict__ A24, float* __restrict__ gw, float* __restrict__ invZ){
  __shared__ float a_lds[Dn];
  __shared__ float logitv[Mn];
  __shared__ float red[12];
  int bk = blockIdx.x; int b = bk / Kk;
  int t = threadIdx.x;
  int p = aidx[bk];
  const float* arow = pt + ((size_t)b*Sn + p) * Dn;
  for (int d = t; d < Dn; d += 256){ float v = arow[d]; a_lds[d] = v; A24[(size_t)bk*Dn + d] = v; }
  __syncthreads();
  float ss = 0.f;
  for (int d = t; d < Dn; d += 256){ float v = a_lds[d]; ss += v*v; }
  float2 rr0 = block_sum2(ss, 0.f, red);
  float na = fmaxf(sqrtf(rr0.x), 1e-6f);
  int lane = t & 63, w = t >> 6;
  for (int mi = 0; mi < 8; mi++){
    int m = w*8 + mi;
    const float* c = cent + (size_t)m * Dn;
    float dt = 0.f, cs = 0.f;
    for (int d = lane; d < Dn; d += 64){ float cv = c[d]; dt += a_lds[d]*cv; cs += cv*cv; }
    #pragma unroll
    for (int off = 32; off > 0; off >>= 1){ dt += __shfl_down(dt, off, 64); cs += __shfl_down(cs, off, 64); }
    if (lane == 0){ float nc = fmaxf(sqrtf(cs), 1e-6f); logitv[m] = dt / (na * nc); }
  }
  __syncthreads();
  if (t == 0){
    float mx = -1e30f;
    for (int m = 0; m < Mn; m++) mx = fmaxf(mx, logitv[m]);
    float sm = 0.f, e[Mn];
    for (int m = 0; m < Mn; m++){ e[m] = expf(logitv[m]-mx); sm += e[m]; }
    float inv = 1.f / sm;
    for (int m = 0; m < Mn; m++) gw[bk*Mn + m] = e[m] * inv;
  }
  // spread normalizer Z
  {
    float zp = 0.f; float ppp = pp[p];
    for (int s2 = t; s2 < Sn; s2 += 256){
      float dd = fabsf(pp[s2] - ppp);
      if (dd <= 8.0f) zp += expf(-dd * 0.125f);
    }
    float2 zr = block_sum2(zp, 0.f, red);
    if (t == 0) invZ[bk] = 1.f / zr.x;
  }
}

// ---------------- low partials: block (dc, m): part[bk][m][dc][r] = sum_{d in chunk} a[bk][d]*ta[m][d][r]
__global__ __launch_bounds__(256) void k_lowpart(const float* __restrict__ ta,
    const float* __restrict__ A24, float* __restrict__ part_low){
  __shared__ float ta_s[64*64];       // [d][r]
  __shared__ float a_s[NBK*64];       // [bk][d]
  int dc = blockIdx.x, m = blockIdx.y;
  int t = threadIdx.x;
  int d0 = dc * 64;
  const float4* src = (const float4*)(ta + ((size_t)m*Dn + d0) * Rn);
  float4* dst = (float4*)ta_s;
  #pragma unroll
  for (int c = 0; c < 4; c++) dst[t + c*256] = src[t + c*256];
  for (int idx = t; idx < NBK*64; idx += 256){
    int bk = idx >> 6, dl = idx & 63;
    a_s[idx] = A24[(size_t)bk*Dn + d0 + dl];
  }
  __syncthreads();
  int r = t & 63, g = t >> 6;
  #pragma unroll
  for (int j = 0; j < 6; j++){
    int bk = g*6 + j;
    float acc = 0.f;
    #pragma unroll 8
    for (int d = 0; d < 64; d++) acc += a_s[bk*64 + d] * ta_s[d*64 + r];
    part_low[(((size_t)bk*Mn + m)*16 + dc)*64 + r] = acc;
  }
}

// ---------------- low final: low[bk][r] = sum_m w * sum_dc part ----------------
__global__ __launch_bounds__(64) void k_lowfin(const float* __restrict__ part_low,
    const float* __restrict__ gw, float* __restrict__ lowb){
  int bk = blockIdx.x, r = threadIdx.x;
  float acc = 0.f;
  for (int m = 0; m < Mn; m++){
    float s = 0.f;
    #pragma unroll
    for (int dc = 0; dc < 16; dc++)
      s += part_low[(((size_t)bk*Mn + m)*16 + dc)*64 + r];
    acc += gw[bk*Mn + m] * s;
  }
  lowb[bk*64 + r] = acc;
}

// ---------------- translated partials: block (dc, m): transp[bk][m][d] = sum_r tb[m][d][r]*low[bk][r]
__global__ __launch_bounds__(256) void k_transpart(const float* __restrict__ tb,
    const float* __restrict__ lowb, float* __restrict__ transp){
  __shared__ float tb_t[64*65];       // [r][d], padded
  __shared__ float low_s[NBK*64];
  int dc = blockIdx.x, m = blockIdx.y;
  int t = threadIdx.x;
  int d0 = dc * 64;
  const float* src = tb + ((size_t)m*Dn + d0) * Rn;
  for (int idx = t; idx < 4096; idx += 256){
    int d = idx >> 6, r = idx & 63;
    tb_t[r*65 + d] = src[idx];
  }
  for (int idx = t; idx < NBK*64; idx += 256) low_s[idx] = lowb[idx];
  __syncthreads();
  int dl = t & 63, g = t >> 6;
  #pragma unroll
  for (int j = 0; j < 6; j++){
    int bk = g*6 + j;
    float acc = 0.f;
    #pragma unroll 8
    for (int r = 0; r < 64; r++) acc += tb_t[r*65 + dl] * low_s[bk*64 + r];
    transp[((size_t)bk*Mn + m)*Dn + d0 + dl] = acc;
  }
}

// ---------------- translated final: transl[bk][d] = sum_m w*transp ----------------
__global__ __launch_bounds__(256) void k_transfin(const float* __restrict__ transp,
    const float* __restrict__ gw, float* __restrict__ transl){
  int bk = blockIdx.x, t = threadIdx.x;
  for (int d = t; d < Dn; d += 256){
    float acc = 0.f;
    #pragma unroll 8
    for (int m = 0; m < Mn; m++)
      acc += gw[bk*Mn + m] * transp[((size_t)bk*Mn + m)*Dn + d];
    transl[(size_t)bk*Dn + d] = acc;
  }
}

// ---------------- transpose f32 [Ks][1024] -> bf16 [1024][Ks] ----------------
__global__ __launch_bounds__(256) void k_transpose(const float* __restrict__ src,
    u16* __restrict__ dst, int Ks){
  __shared__ float tile[32][33];
  int kb = blockIdx.x * 32, nb = blockIdx.y * 32;
  int tx = threadIdx.x & 31, ty = threadIdx.x >> 5;
  #pragma unroll
  for (int r = 0; r < 32; r += 8)
    tile[ty+r][tx] = src[(size_t)(kb+ty+r) * Dn + nb + tx];
  __syncthreads();
  #pragma unroll
  for (int r = 0; r < 32; r += 8)
    dst[(size_t)(nb+ty+r) * Ks + kb + tx] = f2bf(tile[tx][ty+r]);
}

// ---------------- per-row: spread update + 3 LN + gate ----------------
__global__ __launch_bounds__(256) void k_rows(
    const float* __restrict__ ts, const float* __restrict__ pt,
    const float* __restrict__ stab, const float* __restrict__ transl,
    const int* __restrict__ aidx, const float* __restrict__ invZ,
    const float* __restrict__ pp,
    const float* __restrict__ og, const float* __restrict__ ob,
    const float* __restrict__ tgp, const float* __restrict__ tbp,
    const float* __restrict__ pgp, const float* __restrict__ pbp,
    float* __restrict__ ts_aug_out, u16* __restrict__ Xcat, float* __restrict__ gate){
  __shared__ float red[12];
  int row = blockIdx.x; int b = row >> 12; int s = row & 4095;
  int t = threadIdx.x;
  size_t base = (size_t)row * Dn;
  const float4 xin = *(const float4*)(ts + base + 4*t);
  float x0 = xin.x, x1 = xin.y, x2 = xin.z, x3 = xin.w;
  float pps = pp[s];
  for (int k = 0; k < Kk; k++){
    int p = aidx[b*Kk + k];
    float dd = fabsf(pps - pp[p]);
    if (dd <= 8.0f){
      float coef = expf(-dd * 0.125f) * invZ[b*Kk + k];
      const float4 tr = *(const float4*)(transl + ((size_t)(b*Kk + k)) * Dn + 4*t);
      x0 += coef*tr.x; x1 += coef*tr.y; x2 += coef*tr.z; x3 += coef*tr.w;
    }
  }
  float2 r = block_sum2(x0+x1+x2+x3, x0*x0+x1*x1+x2*x2+x3*x3, red);
  float mu = r.x * (1.f/Dn); float var = r.y * (1.f/Dn) - mu*mu;
  float rs = 1.f / sqrtf(var + 1e-5f);
  float4 g4 = *(const float4*)(og + 4*t), b4 = *(const float4*)(ob + 4*t);
  float a0 = (x0-mu)*rs*g4.x + b4.x;
  float a1 = (x1-mu)*rs*g4.y + b4.y;
  float a2 = (x2-mu)*rs*g4.z + b4.z;
  float a3 = (x3-mu)*rs*g4.w + b4.w;
  float4 sto; sto.x=a0; sto.y=a1; sto.z=a2; sto.w=a3;
  *(float4*)(ts_aug_out + base + 4*t) = sto;
  r = block_sum2(a0+a1+a2+a3, a0*a0+a1*a1+a2*a2+a3*a3, red);
  mu = r.x * (1.f/Dn); var = r.y * (1.f/Dn) - mu*mu;
  rs = 1.f / sqrtf(var + 1e-5f);
  g4 = *(const float4*)(tgp + 4*t); b4 = *(const float4*)(tbp + 4*t);
  float t0 = (a0-mu)*rs*g4.x + b4.x;
  float t1 = (a1-mu)*rs*g4.y + b4.y;
  float t2 = (a2-mu)*rs*g4.z + b4.z;
  float t3 = (a3-mu)*rs*g4.w + b4.w;
  const float4 pv = *(const float4*)(pt + base + 4*t);
  r = block_sum2(pv.x+pv.y+pv.z+pv.w, pv.x*pv.x+pv.y*pv.y+pv.z*pv.z+pv.w*pv.w, red);
  mu = r.x * (1.f/Dn); var = r.y * (1.f/Dn) - mu*mu;
  rs = 1.f / sqrtf(var + 1e-5f);
  g4 = *(const float4*)(pgp + 4*t); b4 = *(const float4*)(pbp + 4*t);
  float p0 = (pv.x-mu)*rs*g4.x + b4.x;
  float p1 = (pv.y-mu)*rs*g4.y + b4.y;
  float p2 = (pv.z-mu)*rs*g4.z + b4.z;
  float p3 = (pv.w-mu)*rs*g4.w + b4.w;
  ushort4 pk;
  pk.x = f2bf(t0); pk.y = f2bf(t1); pk.z = f2bf(t2); pk.w = f2bf(t3);
  *(ushort4*)(Xcat + (size_t)row*2048 + 4*t) = pk;
  pk.x = f2bf(p0); pk.y = f2bf(p1); pk.z = f2bf(p2); pk.w = f2bf(p3);
  *(ushort4*)(Xcat + (size_t)row*2048 + Dn + 4*t) = pk;
  float3 rr = block_sum3(t0*p0+t1*p1+t2*p2+t3*p3,
                         t0*t0+t1*t1+t2*t2+t3*t3,
                         p0*p0+p1*p1+p2*p2+p3*p3, red);
  if (t == 0){
    float cosv = rr.x / (fmaxf(sqrtf(rr.y), 1e-6f) * fmaxf(sqrtf(rr.z), 1e-6f));
    float ag = 0.5f * (1.f + cosv);
    float z = (ag - 0.72f) * 5.f;
    float focus = 0.2f + 0.8f * expf(-0.5f*z*z);
    gate[row] = ag * focus * stab[row];
  }
}

// ---------------- 256x256 bf16 MFMA GEMM, 8-phase schedule ----------------
// Changes vs prev round: (a) staging order gives every half-tile >=3.5-phase lead
// (ph1: B-h0(t+1), ph2: A-h1(t+1), ph3: A-h0(t+2), ph4: B-h1(t+2); vmcnt(8) after
// ph2 covers A-h1(t) just before ph3; vmcnt(6) at boundary covers tile t+1's
// ph1/ph2 needs; tail drains vmcnt(0)). (b) LDS-transposed coalesced epilogue:
// acc -> smem (2 chunks of 128x256 f32, col ^ ((row>>2&3)<<4) swizzle = 2-way free)
// -> full-row 1024B coalesced float4 global R/W (replaces scalar 4-rows-x-16-cols scatter).
__global__ __launch_bounds__(512, 2) void k_gemm(
    const u16* __restrict__ A, const u16* __restrict__ Bt, int K, int mode,
    float* __restrict__ out0, const float* __restrict__ sbias, const float* __restrict__ Wlast,
    const float* __restrict__ gate, float* __restrict__ dts,
    const float* __restrict__ ptin, float* __restrict__ dpt, const float* __restrict__ bscale){
  __shared__ __attribute__((aligned(16))) char smem[131072];
  const int NT = K >> 6;
  const int tid = threadIdx.x;
  const int lane = tid & 63, w = tid >> 6;
  const int wm = w >> 2, wn = w & 3;
  const int r15 = lane & 15, quad = lane >> 4;
  // bijective XCD swizzle (512 % 8 == 0)
  const int bid = blockIdx.x;
  const int bm = (bid & 7) * 16 + ((bid >> 3) & 15);
  const int bn = bid >> 7;
  const int m0 = bm * 256, n0 = bn * 256;

  // --- staging: pre-swizzled global source, linear LDS dest ---
  const int row0 = tid >> 3, j0 = tid & 7;
  const int js = j0 ^ (row0 & 7);
  const size_t rowbytes = (size_t)K * 2;
  const char* gA = (const char*)A + (size_t)(m0 + row0) * rowbytes + js * 16;
  const char* gB = (const char*)Bt + (size_t)(n0 + row0) * rowbytes + js * 16;
  const size_t rstep64 = rowbytes << 6;   // 64 rows
  char* lA = smem + tid * 16;
  char* lB = smem + 65536 + tid * 16;

  auto stgA = [&](int half, int tile, int buf){
    const char* s = gA + (size_t)half * (rstep64 << 1) + (size_t)tile * 128;
    char* d = lA + buf * 32768 + half * 16384;
    cp16(s, d); cp16(s + rstep64, d + 8192);
  };
  auto stgB = [&](int half, int tile, int buf){
    const char* s = gB + (size_t)half * (rstep64 << 1) + (size_t)tile * 128;
    char* d = lB + buf * 32768 + half * 16384;
    cp16(s, d); cp16(s + rstep64, d + 8192);
  };

  // --- ds_read fragment byte offsets (same XOR swizzle) ---
  int aoff[4][2], boff[2][2];
  #pragma unroll
  for (int fi = 0; fi < 4; fi++){
    int rl = wm*64 + fi*16 + r15;
    #pragma unroll
    for (int ks = 0; ks < 2; ks++)
      aoff[fi][ks] = rl*128 + ((((ks<<2) + quad) ^ (r15 & 7)) << 4);
  }
  #pragma unroll
  for (int fj = 0; fj < 2; fj++){
    int rn = wn*32 + fj*16 + r15;
    #pragma unroll
    for (int ks = 0; ks < 2; ks++)
      boff[fj][ks] = rn*128 + ((((ks<<2) + quad) ^ (r15 & 7)) << 4);
  }

  short8 ar[4][2];
  short8 br[2][2][2];
  f32x4 acc[8][4];
  #pragma unroll
  for (int i = 0; i < 8; i++)
    #pragma unroll
    for (int j = 0; j < 4; j++){ f32x4 z = {0.f,0.f,0.f,0.f}; acc[i][j] = z; }

  auto rdA = [&](int ph, int buf){
    #pragma unroll
    for (int fi = 0; fi < 4; fi++)
      #pragma unroll
      for (int ks = 0; ks < 2; ks++)
        ar[fi][ks] = *(const short8*)(smem + buf*32768 + ph*16384 + aoff[fi][ks]);
  };
  auto rdB = [&](int p, int buf){
    #pragma unroll
    for (int fj = 0; fj < 2; fj++)
      #pragma unroll
      for (int ks = 0; ks < 2; ks++)
        br[p][fj][ks] = *(const short8*)(smem + 65536 + buf*32768 + p*16384 + boff[fj][ks]);
  };
  auto mma16 = [&](int ap, int bp){
    __builtin_amdgcn_s_barrier();
    asm volatile("s_waitcnt lgkmcnt(0)" ::: "memory");
    __builtin_amdgcn_sched_barrier(0);
    __builtin_amdgcn_s_setprio(1);
    #pragma unroll
    for (int fi = 0; fi < 4; fi++)
      #pragma unroll
      for (int fj = 0; fj < 2; fj++)
        #pragma unroll
        for (int ks = 0; ks < 2; ks++)
          acc[ap*4+fi][bp*2+fj] = __builtin_amdgcn_mfma_f32_16x16x32_bf16(
              ar[fi][ks], br[bp][fj][ks], acc[ap*4+fi][bp*2+fj], 0, 0, 0);
    __builtin_amdgcn_s_setprio(0);
  };

  // --- prologue: tile0 all 4 half-tiles (buf0) + tile1's A-h0, B-h1 (buf1) ---
  stgA(0, 0, 0); stgA(1, 0, 0); stgB(0, 0, 0); stgB(1, 0, 0);
  stgA(0, 1, 1); stgB(1, 1, 1);
  asm volatile("s_waitcnt vmcnt(4)" ::: "memory");   // all of tile0 landed
  __builtin_amdgcn_s_barrier();

  auto tileStep = [&](int t, int buf){
    // ph1: (A-h0 x B-h0)
    rdA(0, buf); rdB(0, buf);
    if (t+1 < NT) stgB(0, t+1, buf^1);
    mma16(0, 0);
    __builtin_amdgcn_s_barrier();
    // ph2: (A-h0 x B-h1)
    rdB(1, buf);
    if (t+1 < NT) stgA(1, t+1, buf^1);
    mma16(0, 1);
    asm volatile("s_waitcnt vmcnt(8)" ::: "memory"); // A-h1(t) landed (for ph3)
    __builtin_amdgcn_s_barrier();
    // ph3: (A-h1 x B-h1)
    rdA(1, buf);
    if (t+2 < NT) stgA(0, t+2, buf);
    mma16(1, 1);
    __builtin_amdgcn_s_barrier();
    // ph4: (A-h1 x B-h0), B-h0 regs kept from ph1
    if (t+2 < NT) stgB(1, t+2, buf);
    mma16(1, 0);
    if (t+2 < NT){ asm volatile("s_waitcnt vmcnt(6)" ::: "memory"); }
    else         { asm volatile("s_waitcnt vmcnt(0)" ::: "memory"); }
    __builtin_amdgcn_s_barrier();
  };
  for (int t = 0; t < NT; t += 2){ tileStep(t, 0); tileStep(t+1, 1); }

  // --- epilogue: LDS-transposed coalesced C-write ---
  float blend = 0.f;
  if (mode != 0) blend = 0.35f / (1.f + expf(-bscale[0]));
  float* lC = (float*)smem;                 // [128][256] f32 per chunk
  const int cols0 = n0 + lane*4;
  float4 sb4 = {0.f,0.f,0.f,0.f}, wl4 = {0.f,0.f,0.f,0.f};
  if (mode == 0){
    sb4 = *(const float4*)(sbias + cols0);
    wl4 = *(const float4*)(Wlast + cols0);
  }
  #pragma unroll
  for (int c = 0; c < 2; c++){
    __builtin_amdgcn_s_barrier();           // previous readers of smem done
    #pragma unroll
    for (int mi2 = 0; mi2 < 4; mi2++){
      int mi = c*4 + mi2;
      int lrow = wm*64 + mi2*16 + quad*4;   // chunk-local row base
      #pragma unroll
      for (int nj = 0; nj < 4; nj++){
        int col = (nj>>1)*128 + wn*32 + (nj&1)*16 + r15;
        #pragma unroll
        for (int rg = 0; rg < 4; rg++){
          int rr = lrow + rg;
          lC[rr*256 + (col ^ (((rr>>2)&3)<<4))] = acc[mi][nj][rg];
        }
      }
    }
    __builtin_amdgcn_s_barrier();
    #pragma unroll
    for (int r = 0; r < 16; r++){
      int rr = w*16 + r;
      int grow = m0 + c*128 + rr;
      float4 v = *(const float4*)(lC + rr*256 + ((lane*4) ^ (((rr>>2)&3)<<4)));
      size_t gi = (size_t)grow * Dn + cols0;
      if (mode == 0){
        float g = gate[grow];
        float4 o;
        o.x = v.x + sb4.x + g*wl4.x; o.y = v.y + sb4.y + g*wl4.y;
        o.z = v.z + sb4.z + g*wl4.z; o.w = v.w + sb4.w + g*wl4.w;
        *(float4*)(out0 + gi) = o;
      } else if (mode == 1){
        float bg = blend * gate[grow];
        float4 d = *(const float4*)(dts + gi);
        d.x += bg*v.x; d.y += bg*v.y; d.z += bg*v.z; d.w += bg*v.w;
        *(float4*)(dts + gi) = d;
      } else {
        float bg = blend * gate[grow];
        float4 p = *(const float4*)(ptin + gi);
        p.x += bg*v.x; p.y += bg*v.y; p.z += bg*v.z; p.w += bg*v.w;
        *(float4*)(dpt + gi) = p;
      }
    }
  }
}

// ---------------- causal pool (k=3) + diffs vs tsn/ptn, bf16 ----------------
__global__ __launch_bounds__(256) void k_pooldiff(const float* __restrict__ sh,
    const u16* __restrict__ Xcat, u16* __restrict__ Xts, u16* __restrict__ Xpt){
  int row = blockIdx.x; int s = row & 4095; int t = threadIdx.x;
  size_t base = (size_t)row * Dn + 4*t;
  int rm1 = (s >= 1) ? row-1 : row;
  int rm2 = (s >= 2) ? row-2 : rm1;
  float4 a = *(const float4*)(sh + base);
  float4 b = *(const float4*)(sh + (size_t)rm1*Dn + 4*t);
  float4 c = *(const float4*)(sh + (size_t)rm2*Dn + 4*t);
  float p0 = (a.x+b.x+c.x)*(1.f/3.f);
  float p1 = (a.y+b.y+c.y)*(1.f/3.f);
  float p2 = (a.z+b.z+c.z)*(1.f/3.f);
  float p3 = (a.w+b.w+c.w)*(1.f/3.f);
  ushort4 tn = *(const ushort4*)(Xcat + (size_t)row*2048 + 4*t);
  ushort4 pn = *(const ushort4*)(Xcat + (size_t)row*2048 + Dn + 4*t);
  ushort4 o;
  o.x = f2bf(p0 - bf2f(tn.x)); o.y = f2bf(p1 - bf2f(tn.y));
  o.z = f2bf(p2 - bf2f(tn.z)); o.w = f2bf(p3 - bf2f(tn.w));
  *(ushort4*)(Xts + base) = o;
  o.x = f2bf(p0 - bf2f(pn.x)); o.y = f2bf(p1 - bf2f(pn.y));
  o.z = f2bf(p2 - bf2f(pn.z)); o.w = f2bf(p3 - bf2f(pn.w));
  *(ushort4*)(Xpt + base) = o;
}

extern "C" void kernel_launch(void* const* d_in, const int* in_sizes, int n_in,
                              void* d_out, int out_size, void* d_ws, size_t ws_size,
                              hipStream_t stream){
  const float* pt   = (const float*)d_in[0];
  const float* ts   = (const float*)d_in[1];
  const float* pp   = (const float*)d_in[2];
  const float* cent = (const float*)d_in[3];
  const float* stab = (const float*)d_in[4];
  const float* aw   = (const float*)d_in[5];
  const float* ab   = (const float*)d_in[6];
  const float* ta   = (const float*)d_in[7];
  const float* tb   = (const float*)d_in[8];
  const float* og   = (const float*)d_in[9];
  const float* ob   = (const float*)d_in[10];
  const float* tg   = (const float*)d_in[11];
  const float* tbn  = (const float*)d_in[12];
  const float* pg   = (const float*)d_in[13];
  const float* pb   = (const float*)d_in[14];
  const float* sW   = (const float*)d_in[15];
  const float* sb   = (const float*)d_in[16];
  const float* tsW  = (const float*)d_in[17];
  const float* ptW  = (const float*)d_in[18];
  const float* bsc  = (const float*)d_in[19];
  float* out_ts = (float*)d_out;
  float* out_pt = out_ts + (size_t)BSn * Dn;

  char* wbase = (char*)d_ws; size_t off = 0;
  auto alloc = [&](size_t bytes) -> void* {
    void* p = wbase + off;
    off += (bytes + 255) & ~(size_t)255;
    return p;
  };
  float* scores  = (float*)alloc((size_t)BSn * 4);
  int*   aidx    = (int*)  alloc(256);
  float* invZ    = (float*)alloc(256);
  float* transl  = (float*)alloc((size_t)NBK*Dn * 4);
  float* gate    = (float*)alloc((size_t)BSn * 4);
  float* A24     = (float*)alloc((size_t)NBK*Dn * 4);
  float* gw      = (float*)alloc((size_t)NBK*Mn * 4);
  float* part_low= (float*)alloc((size_t)NBK*Mn*16*64 * 4);
  float* lowb    = (float*)alloc((size_t)NBK*64 * 4);
  float* transp  = (float*)alloc((size_t)NBK*Mn*Dn * 4);
  u16*   Xcat    = (u16*)  alloc((size_t)BSn * 2048 * 2);
  float* shmem   = (float*)alloc((size_t)BSn * Dn * 4);
  u16*   Xts     = (u16*)  alloc((size_t)BSn * Dn * 2);
  u16*   Xpt     = (u16*)  alloc((size_t)BSn * Dn * 2);
  u16*   WtS     = (u16*)  alloc((size_t)Dn * 2048 * 2);
  u16*   WtT     = (u16*)  alloc((size_t)Dn * Dn * 2);
  u16*   WtP     = (u16*)  alloc((size_t)Dn * Dn * 2);

  k_scores<<<BSn/4, 256, 0, stream>>>(pt, aw, ab, scores);
  k_top3<<<Bn, 256, 0, stream>>>(scores, aidx);
  k_adapter_w<<<NBK, 256, 0, stream>>>(pt, cent, pp, aidx, A24, gw, invZ);
  k_lowpart<<<dim3(16, Mn), 256, 0, stream>>>(ta, A24, part_low);
  k_lowfin<<<NBK, 64, 0, stream>>>(part_low, gw, lowb);
  k_transpart<<<dim3(16, Mn), 256, 0, stream>>>(tb, lowb, transp);
  k_transfin<<<NBK, 256, 0, stream>>>(transp, gw, transl);
  k_transpose<<<dim3(64,32), 256, 0, stream>>>(sW, WtS, 2048);
  k_transpose<<<dim3(32,32), 256, 0, stream>>>(tsW, WtT, 1024);
  k_transpose<<<dim3(32,32), 256, 0, stream>>>(ptW, WtP, 1024);
  k_rows<<<BSn, 256, 0, stream>>>(ts, pt, stab, transl, aidx, invZ, pp,
                                  og, ob, tg, tbn, pg, pb, out_ts, Xcat, gate);
  k_gemm<<<512, 512, 0, stream>>>(Xcat, WtS, 2048, 0,
      shmem, sb, sW + (size_t)2048*Dn, gate, nullptr, nullptr, nullptr, bsc);
  k_pooldiff<<<BSn, 256, 0, stream>>>(shmem, Xcat, Xts, Xpt);
  k_gemm<<<512, 512, 0, stream>>>(Xts, WtT, 1024, 1,
      nullptr, nullptr, nullptr, gate, out_ts, nullptr, nullptr, bsc);
  k_gemm<<<512, 512, 0, stream>>>(Xpt, WtP, 1024, 2,
      nullptr, nullptr, nullptr, gate, nullptr, pt, out_pt, bsc);
}